// Round 17
// baseline (90.431 us; speedup 1.0000x reference)
//
#include <hip/hip_runtime.h>

// AttentionConvFull: grouped 1x1 QKV + 5x5 per-channel local attention, FUSED.
// B=4, H=W=56, C=OC=256, G=8, Cg=32, K=5, pad=2.
//
// R17 = R16 structure + WEIGHT RESIDENCY experiment:
//   - weights held as float4 arrays (R13 proved this forces register
//     residency: VGPR jumped to cap) and loaded BEFORE staging,
//   - __launch_bounds__(256,1): cap 256, so natural demand (~115-145) fits
//     WITHOUT spill (R13's failure was cap 128 < demand).
// Mechanism: R16 counters (VALUBusy 46%, wall 60us, VALU issue ~25us) say
// the merged pass stalls on per-iteration L1 weight reloads (VGPR 72 cannot
// hold the 96-float weight set). Residency removes ~18 x ~200cy exposed
// latency per thread. Risk: if VGPR lands 129-170 -> 3 waves/SIMD (neutral);
// >170 -> 2 waves/SIMD (revert next round).
//
//   Stage:   x halo (12x12 px, 32 ch) -> xs LDS, coalesced float4, OOB zeroed.
//   Merged QKV pass (18 iters, 3 chains, float4 weights resident).
//            k,v packed bf16x2 in one u32, overwriting xs in place (row's
//            only reader+writer is its owning half-wave; reads precede
//            writes; per-wave in-order DS => race-free). q*log2e -> qs (f32).
//   Phase C: monolithic 8-pixel row-streaming attention; k,v,rel bf16-
//            unpacked on use; native exp2 + rcp; single-pass softmax.
// 2 barriers.
//
// Register law (R1-R16): cap = 256/N for __launch_bounds__(256,N); no bounds
// => 64 cap. Forcing a cap below natural demand spills (R13 128+64MB WRITE,
// R14 64+30MB, R15 64+191MB). Natural floor of the R12/R16 shape is 72.
// Spill signature: VGPR==cap AND WRITE >> 12.5MB logical.
// Precision ledger: bf16 k,v + bf16 rel measured absmax 2.34e-2 (R14/R16);
// threshold 5.69e-2.

constexpr int TB = 4, TH = 56, TW = 56, TC = 256;
constexpr int G  = 8, CG = 32, PAD = 2;
constexpr int TILE = 8;
constexpr int HT = TILE + 2 * PAD;   // 12
constexpr int NT = TH / TILE;        // 7
constexpr int NPIX_HALO = HT * HT;   // 144
constexpr float LOG2E = 1.44269504088896340736f;

__global__ __launch_bounds__(256, 1)
void fused_attn_conv_kernel(const float* __restrict__ x,
                            const float* __restrict__ wq,
                            const float* __restrict__ wk,
                            const float* __restrict__ wv,
                            const float* __restrict__ rel,
                            const float* __restrict__ qemb,
                            float* __restrict__ out) {
    __shared__ float xs[NPIX_HALO][CG];    // 18 KB: x halo, then packed bf16(k,v)
    __shared__ float qs[TILE * TILE][CG];  // 8 KB: q*log2e for interior pixels

    const int bid  = blockIdx.x;
    const int g    = bid & 7;
    const int tile = bid >> 3;
    const int tj   = tile % NT;
    const int ti   = (tile / NT) % NT;
    const int b    = tile / (NT * NT);

    const int t  = threadIdx.x;
    const int c  = t & 31;
    const int p0 = t >> 5;

    const int oc = g * CG + c;           // global out-channel
    const int h0 = ti * TILE - PAD, w0 = tj * TILE - PAD;

    // ---- Weight loads FIRST (latency overlaps staging); float4-typed so
    //      they stay register-resident (R13 evidence; cap 256 => no spill).
    float4 wq4[8], wk4[8], wv4[8];
    {
        const float4* wqp = (const float4*)(wq + (size_t)oc * CG);
        const float4* wkp = (const float4*)(wk + (size_t)oc * CG);
        const float4* wvp = (const float4*)(wv + (size_t)oc * CG);
#pragma unroll
        for (int i = 0; i < 8; ++i) { wq4[i] = wqp[i]; wk4[i] = wkp[i]; wv4[i] = wvp[i]; }
    }
    const float qe = qemb[oc];

    // ---- Stage: x halo -> xs, coalesced float4 (1152 float4 over 256 thr).
#pragma unroll
    for (int r = 0; r < 5; ++r) {
        const int f = t + r * 256;
        if (f < NPIX_HALO * CG / 4) {
            const int hp = f >> 3, c4 = f & 7;        // 8 float4 per pixel
            const int hi = hp / HT, hj = hp % HT;
            const int gh = h0 + hi, gw = w0 + hj;
            float4 val = make_float4(0.f, 0.f, 0.f, 0.f);
            if (gh >= 0 && gh < TH && gw >= 0 && gw < TW)
                val = *(const float4*)(x + (((size_t)b * TH + gh) * TW + gw) * TC
                                         + g * CG + c4 * 4);
            *(float4*)&xs[hp][c4 * 4] = val;
        }
    }

    __syncthreads();   // stage -> merged pass

    // ---- Merged QKV pass over all 144 halo pixels (1 px/iter, 3 chains).
#pragma unroll 1
    for (int it = 0; it < NPIX_HALO / 8; ++it) {
        const int hp = it * 8 + p0;
        const int hi = hp / HT, hj = hp % HT;
        const float4* xp = (const float4*)&xs[hp][0];
        float aq = qe, ak = 0.f, av = 0.f;
#pragma unroll
        for (int i = 0; i < 8; ++i) {
            const float4 xv = xp[i];   // LDS broadcast within half-wave
            const float4 q4 = wq4[i], k4 = wk4[i], v4 = wv4[i];
            aq = fmaf(q4.x, xv.x, aq); ak = fmaf(k4.x, xv.x, ak); av = fmaf(v4.x, xv.x, av);
            aq = fmaf(q4.y, xv.y, aq); ak = fmaf(k4.y, xv.y, ak); av = fmaf(v4.y, xv.y, av);
            aq = fmaf(q4.z, xv.z, aq); ak = fmaf(k4.z, xv.z, ak); av = fmaf(v4.z, xv.z, av);
            aq = fmaf(q4.w, xv.w, aq); ak = fmaf(k4.w, xv.w, ak); av = fmaf(v4.w, xv.w, av);
        }
        // pack k,v -> bf16 (round-half-up) in one u32; overwrite xs row
        // in place (all reads of this row happened above, same lanes).
        const unsigned kb = __float_as_uint(ak) + 0x8000u;
        const unsigned vb = __float_as_uint(av) + 0x8000u;
        ((unsigned*)&xs[hp][0])[c] = (kb >> 16) | (vb & 0xffff0000u);
        if (hi >= PAD && hi < PAD + TILE && hj >= PAD && hj < PAD + TILE)
            qs[(hi - PAD) * TILE + (hj - PAD)][c] = aq * LOG2E;
    }

    // rel row -> 13 packed bf16 pairs (even idx = low half, odd = high half)
    unsigned relp[13];
    {
        const float* rp = rel + (size_t)oc * 25;
#pragma unroll
        for (int i = 0; i < 12; ++i) {
            const unsigned lo = __float_as_uint(rp[2 * i])     + 0x8000u;
            const unsigned hi = __float_as_uint(rp[2 * i + 1]) + 0x8000u;
            relp[i] = (lo >> 16) | (hi & 0xffff0000u);
        }
        relp[12] = (__float_as_uint(rp[24]) + 0x8000u) >> 16;
    }

    __syncthreads();   // merged pass -> C

    // q (already *log2e) for this thread's 8 column pixels
    float qreg[8];
#pragma unroll
    for (int ii = 0; ii < 8; ++ii) qreg[ii] = qs[ii * TILE + p0][c];

    // ---- Phase C: monolithic row-streaming attention (xs holds bf16 k,v).
    float s_[8], a_[8];
#pragma unroll
    for (int ii = 0; ii < 8; ++ii) { s_[ii] = 0.f; a_[ii] = 0.f; }

    const unsigned* kvp = (const unsigned*)&xs[0][0];
#pragma unroll
    for (int h = 0; h < HT; ++h) {
        float kr[5], vr[5];
#pragma unroll
        for (int j = 0; j < 5; ++j) {
            const unsigned u = kvp[(h * HT + p0 + j) * CG + c];
            kr[j] = __uint_as_float(u << 16);          // bf16 k -> f32
            vr[j] = __uint_as_float(u & 0xffff0000u);  // bf16 v -> f32
        }
#pragma unroll
        for (int ii = 0; ii < 8; ++ii) {
            const int di = h - ii;               // compile-time after unroll
            if (di >= 0 && di < 5) {
                const float qv = qreg[ii];
#pragma unroll
                for (int j = 0; j < 5; ++j) {
                    const int idx = di * 5 + j;  // compile-time
                    const unsigned ru = relp[idx >> 1];
                    const float rl = __uint_as_float((idx & 1) ? (ru & 0xffff0000u)
                                                               : (ru << 16));
                    const float e = __builtin_amdgcn_exp2f(qv * (kr[j] + rl));
                    s_[ii] += e;
                    a_[ii] = fmaf(e, vr[j], a_[ii]);
                }
            }
        }
    }

#pragma unroll
    for (int ii = 0; ii < 8; ++ii) {
        const int gh = ti * TILE + ii, gw = tj * TILE + p0;
        out[(((size_t)b * TH + gh) * TW + gw) * TC + g * CG + c] =
            a_[ii] * __builtin_amdgcn_rcpf(s_[ii]);
    }
}

extern "C" void kernel_launch(void* const* d_in, const int* in_sizes, int n_in,
                              void* d_out, int out_size, void* d_ws, size_t ws_size,
                              hipStream_t stream) {
    const float* x    = (const float*)d_in[0];
    const float* wq   = (const float*)d_in[1];
    const float* wk   = (const float*)d_in[2];
    const float* wv   = (const float*)d_in[3];
    const float* rel  = (const float*)d_in[4];
    const float* qemb = (const float*)d_in[5];
    float* out = (float*)d_out;

    const int nblocks = TB * NT * NT * G;   // 4*7*7*8 = 1568
    hipLaunchKernelGGL(fused_attn_conv_kernel, dim3(nblocks), dim3(256), 0, stream,
                       x, wq, wk, wv, rel, qemb, out);
}

// Round 19
// 59.816 us; speedup vs baseline: 1.5118x; 1.5118x over previous
//
#include <hip/hip_runtime.h>

// AttentionConvFull: grouped 1x1 QKV + 5x5 per-channel local attention, FUSED.
// B=4, H=W=56, C=OC=256, G=8, Cg=32, K=5, pad=2.
//
// R19 = R18 with the type fix: half2_t must be __fp16-vector (that's what
// __builtin_amdgcn_cvt_pkrtz returns / __builtin_amdgcn_fdot2 consumes).
//
// Projection via v_dot2_f32_f16 (2 MACs/instr, f32 accumulate):
//   - x staged into LDS as packed f16 pairs (cvt_pkrtz at stage time):
//     merged-pass VALU 96 FMA -> 48 dot2 per pixel, b128 reads 8 -> 4/px.
//   - weights converted ONCE to 48 packed half2 regs; demand ~75-115 < cap
//     128 => stays resident (R13: vector-typed arrays resident under cap).
//   - k,v packed bf16x2 -> kvs; phase C unchanged from R16 (proven).
// LDS: xs16 9KB + kvs 18KB + qs 8KB = 35KB -> 4 blocks/CU (matches the
// 4-waves/SIMD band; no occupancy loss vs R16).
//
// R13-R17 lessons (occupancy axis exhausted): natural VGPR floor of the f32
// structure is 72; forcing cap 64 spills (WRITE 30-191MB); resident f32
// weights -> VGPR 144 -> 3-wave band -> 105us. Champion R16 53.2us.
// This round cuts VALU work (~3900 -> ~2900 slots/thread) + LDS b128 traffic.
//
// Precision ledger: bf16 k,v + bf16 rel = 2.34e-2 measured (R14/R16/R17);
// f16 x/weights adds ~1e-3 (2^-11 rel, f32 accum). Threshold 5.69e-2.
// Spill signature check: VGPR==cap(128) AND WRITE >> 12.5MB logical.

constexpr int TB = 4, TH = 56, TW = 56, TC = 256;
constexpr int G  = 8, CG = 32, PAD = 2;
constexpr int TILE = 8;
constexpr int HT = TILE + 2 * PAD;   // 12
constexpr int NT = TH / TILE;        // 7
constexpr int NPIX_HALO = HT * HT;   // 144
constexpr float LOG2E = 1.44269504088896340736f;

typedef __fp16 half2_t __attribute__((ext_vector_type(2)));

__device__ __forceinline__ half2_t u32_as_h2(unsigned u) {
    union { unsigned u; half2_t h; } cv; cv.u = u; return cv.h;
}
__device__ __forceinline__ unsigned h2_as_u32(half2_t h) {
    union { unsigned u; half2_t h; } cv; cv.h = h; return cv.u;
}

__global__ __launch_bounds__(256, 2)
void fused_attn_conv_kernel(const float* __restrict__ x,
                            const float* __restrict__ wq,
                            const float* __restrict__ wk,
                            const float* __restrict__ wv,
                            const float* __restrict__ rel,
                            const float* __restrict__ qemb,
                            float* __restrict__ out) {
    __shared__ unsigned xs16[NPIX_HALO][CG / 2];   // 9 KB: x halo as f16 pairs
    __shared__ unsigned kvs[NPIX_HALO][CG];        // 18 KB: packed bf16 (k,v)
    __shared__ float    qs[TILE * TILE][CG];       // 8 KB: q*log2e (interior)

    const int bid  = blockIdx.x;
    const int g    = bid & 7;
    const int tile = bid >> 3;
    const int tj   = tile % NT;
    const int ti   = (tile / NT) % NT;
    const int b    = tile / (NT * NT);

    const int t  = threadIdx.x;
    const int c  = t & 31;
    const int p0 = t >> 5;

    const int oc = g * CG + c;           // global out-channel
    const int h0 = ti * TILE - PAD, w0 = tj * TILE - PAD;

    // ---- Weights: load f32, convert ONCE to packed half2 (48 u32 regs).
    half2_t wq2[16], wk2[16], wv2[16];
    {
        const float4* wqp = (const float4*)(wq + (size_t)oc * CG);
        const float4* wkp = (const float4*)(wk + (size_t)oc * CG);
        const float4* wvp = (const float4*)(wv + (size_t)oc * CG);
#pragma unroll
        for (int i = 0; i < 8; ++i) {
            const float4 a = wqp[i], bb = wkp[i], cc = wvp[i];
            wq2[2*i]   = __builtin_amdgcn_cvt_pkrtz(a.x, a.y);
            wq2[2*i+1] = __builtin_amdgcn_cvt_pkrtz(a.z, a.w);
            wk2[2*i]   = __builtin_amdgcn_cvt_pkrtz(bb.x, bb.y);
            wk2[2*i+1] = __builtin_amdgcn_cvt_pkrtz(bb.z, bb.w);
            wv2[2*i]   = __builtin_amdgcn_cvt_pkrtz(cc.x, cc.y);
            wv2[2*i+1] = __builtin_amdgcn_cvt_pkrtz(cc.z, cc.w);
        }
    }
    const float qe = qemb[oc];

    // ---- Stage: x halo -> xs16 (f16 pairs), coalesced float4 reads.
#pragma unroll
    for (int r = 0; r < 5; ++r) {
        const int f = t + r * 256;
        if (f < NPIX_HALO * CG / 4) {
            const int hp = f >> 3, c4 = f & 7;        // 8 float4 per pixel
            const int hi = hp / HT, hj = hp % HT;
            const int gh = h0 + hi, gw = w0 + hj;
            float4 val = make_float4(0.f, 0.f, 0.f, 0.f);
            if (gh >= 0 && gh < TH && gw >= 0 && gw < TW)
                val = *(const float4*)(x + (((size_t)b * TH + gh) * TW + gw) * TC
                                         + g * CG + c4 * 4);
            uint2 p;
            p.x = h2_as_u32(__builtin_amdgcn_cvt_pkrtz(val.x, val.y));
            p.y = h2_as_u32(__builtin_amdgcn_cvt_pkrtz(val.z, val.w));
            *(uint2*)&xs16[hp][c4 * 2] = p;
        }
    }

    __syncthreads();   // stage -> merged pass

    // ---- Merged QKV pass over all 144 halo pixels: 48 dot2/px, 4 b128/px.
#pragma unroll 1
    for (int it = 0; it < NPIX_HALO / 8; ++it) {
        const int hp = it * 8 + p0;
        const int hi = hp / HT, hj = hp % HT;
        const uint4* xp = (const uint4*)&xs16[hp][0];
        float aq = qe, ak = 0.f, av = 0.f;
#pragma unroll
        for (int i = 0; i < 4; ++i) {
            const uint4 xv = xp[i];   // 8 channels (LDS broadcast)
            const half2_t x0 = u32_as_h2(xv.x), x1 = u32_as_h2(xv.y);
            const half2_t x2 = u32_as_h2(xv.z), x3 = u32_as_h2(xv.w);
            aq = __builtin_amdgcn_fdot2(x0, wq2[4*i+0], aq, false);
            ak = __builtin_amdgcn_fdot2(x0, wk2[4*i+0], ak, false);
            av = __builtin_amdgcn_fdot2(x0, wv2[4*i+0], av, false);
            aq = __builtin_amdgcn_fdot2(x1, wq2[4*i+1], aq, false);
            ak = __builtin_amdgcn_fdot2(x1, wk2[4*i+1], ak, false);
            av = __builtin_amdgcn_fdot2(x1, wv2[4*i+1], av, false);
            aq = __builtin_amdgcn_fdot2(x2, wq2[4*i+2], aq, false);
            ak = __builtin_amdgcn_fdot2(x2, wk2[4*i+2], ak, false);
            av = __builtin_amdgcn_fdot2(x2, wv2[4*i+2], av, false);
            aq = __builtin_amdgcn_fdot2(x3, wq2[4*i+3], aq, false);
            ak = __builtin_amdgcn_fdot2(x3, wk2[4*i+3], ak, false);
            av = __builtin_amdgcn_fdot2(x3, wv2[4*i+3], av, false);
        }
        // pack k,v -> bf16 (round-half-up) in one u32 -> kvs
        const unsigned kb = __float_as_uint(ak) + 0x8000u;
        const unsigned vb = __float_as_uint(av) + 0x8000u;
        kvs[hp][c] = (kb >> 16) | (vb & 0xffff0000u);
        if (hi >= PAD && hi < PAD + TILE && hj >= PAD && hj < PAD + TILE)
            qs[(hi - PAD) * TILE + (hj - PAD)][c] = aq * LOG2E;
    }

    // rel row -> 13 packed bf16 pairs (even idx = low half, odd = high half)
    unsigned relp[13];
    {
        const float* rp = rel + (size_t)oc * 25;
#pragma unroll
        for (int i = 0; i < 12; ++i) {
            const unsigned lo = __float_as_uint(rp[2 * i])     + 0x8000u;
            const unsigned hi = __float_as_uint(rp[2 * i + 1]) + 0x8000u;
            relp[i] = (lo >> 16) | (hi & 0xffff0000u);
        }
        relp[12] = (__float_as_uint(rp[24]) + 0x8000u) >> 16;
    }

    __syncthreads();   // merged pass -> C

    // q (already *log2e) for this thread's 8 column pixels
    float qreg[8];
#pragma unroll
    for (int ii = 0; ii < 8; ++ii) qreg[ii] = qs[ii * TILE + p0][c];

    // ---- Phase C: monolithic row-streaming attention (R16 shape, proven).
    float s_[8], a_[8];
#pragma unroll
    for (int ii = 0; ii < 8; ++ii) { s_[ii] = 0.f; a_[ii] = 0.f; }

    const unsigned* kvp = (const unsigned*)&kvs[0][0];
#pragma unroll
    for (int h = 0; h < HT; ++h) {
        float kr[5], vr[5];
#pragma unroll
        for (int j = 0; j < 5; ++j) {
            const unsigned u = kvp[(h * HT + p0 + j) * CG + c];
            kr[j] = __uint_as_float(u << 16);          // bf16 k -> f32
            vr[j] = __uint_as_float(u & 0xffff0000u);  // bf16 v -> f32
        }
#pragma unroll
        for (int ii = 0; ii < 8; ++ii) {
            const int di = h - ii;               // compile-time after unroll
            if (di >= 0 && di < 5) {
                const float qv = qreg[ii];
#pragma unroll
                for (int j = 0; j < 5; ++j) {
                    const int idx = di * 5 + j;  // compile-time
                    const unsigned ru = relp[idx >> 1];
                    const float rl = __uint_as_float((idx & 1) ? (ru & 0xffff0000u)
                                                               : (ru << 16));
                    const float e = __builtin_amdgcn_exp2f(qv * (kr[j] + rl));
                    s_[ii] += e;
                    a_[ii] = fmaf(e, vr[j], a_[ii]);
                }
            }
        }
    }

#pragma unroll
    for (int ii = 0; ii < 8; ++ii) {
        const int gh = ti * TILE + ii, gw = tj * TILE + p0;
        out[(((size_t)b * TH + gh) * TW + gw) * TC + g * CG + c] =
            a_[ii] * __builtin_amdgcn_rcpf(s_[ii]);
    }
}

extern "C" void kernel_launch(void* const* d_in, const int* in_sizes, int n_in,
                              void* d_out, int out_size, void* d_ws, size_t ws_size,
                              hipStream_t stream) {
    const float* x    = (const float*)d_in[0];
    const float* wq   = (const float*)d_in[1];
    const float* wk   = (const float*)d_in[2];
    const float* wv   = (const float*)d_in[3];
    const float* rel  = (const float*)d_in[4];
    const float* qemb = (const float*)d_in[5];
    float* out = (float*)d_out;

    const int nblocks = TB * NT * NT * G;   // 4*7*7*8 = 1568
    hipLaunchKernelGGL(fused_attn_conv_kernel, dim3(nblocks), dim3(256), 0, stream,
                       x, wq, wk, wv, rel, qemb, out);
}

// Round 20
// 52.210 us; speedup vs baseline: 1.7321x; 1.1457x over previous
//
#include <hip/hip_runtime.h>

// AttentionConvFull: grouped 1x1 QKV + 5x5 per-channel local attention, FUSED.
// B=4, H=W=56, C=OC=256, G=8, Cg=32, K=5, pad=2.
//
// R20 = R16 body EXACTLY (champion 53.2us, VGPR 72, spill-free) with ONE
// change: __launch_bounds__(256, 3).
// Hypothesis (from R9/R16 occupancy ledger): the 2nd arg acts as the
// RESIDENCY limiter (2 -> 2 blocks/CU = 8 waves = ~25% measured), while the
// VGPR band (72 -> 4 waves/SIMD) and LDS (26.6KB -> 6 blocks/CU) would allow
// more. (256,3): cap 256/3~85 > 72 natural demand -> NO spill pressure
// (unlike (256,4) cap 64, proven to spill R14/R15), and requests 3 waves/EU.
//
//   Stage:   x halo (12x12 px, 32 ch) -> xs LDS, coalesced float4, OOB zeroed.
//   Merged QKV pass (18 iters, 3 chains): weights demote to L1 reloads (fine).
//            k,v packed bf16x2 in one u32, overwriting xs in place (row's
//            only reader+writer is its owning half-wave; reads precede
//            writes; per-wave in-order DS => race-free). q*log2e -> qs (f32).
//   Phase C: monolithic 8-pixel row-streaming attention; k,v,rel bf16-
//            unpacked on use; native exp2 + rcp; single-pass softmax.
// 2 barriers. LDS 26.6 KB.
//
// Register law (R1-R19): cap = 256/N for __launch_bounds__(256,N); no bounds
// => 64 cap. Natural demand of this structure: 72 (R12/R16). Forcing caps
// below demand spills (R13 128cap+f4weights->64MB WRITE; R14/R15 64cap->
// 30-191MB; R19 128cap+48 h2 weights->51MB). Resident weights at cap 256 ->
// VGPR 144 -> 3-wave band -> 105us (R17). Spill check: VGPR==cap AND
// WRITE >> 12.5MB.
// Precision ledger: bf16 k,v + bf16 rel = 2.34e-2 measured; threshold 5.69e-2.

constexpr int TB = 4, TH = 56, TW = 56, TC = 256;
constexpr int G  = 8, CG = 32, PAD = 2;
constexpr int TILE = 8;
constexpr int HT = TILE + 2 * PAD;   // 12
constexpr int NT = TH / TILE;        // 7
constexpr int NPIX_HALO = HT * HT;   // 144
constexpr float LOG2E = 1.44269504088896340736f;

__global__ __launch_bounds__(256, 3)
void fused_attn_conv_kernel(const float* __restrict__ x,
                            const float* __restrict__ wq,
                            const float* __restrict__ wk,
                            const float* __restrict__ wv,
                            const float* __restrict__ rel,
                            const float* __restrict__ qemb,
                            float* __restrict__ out) {
    __shared__ float xs[NPIX_HALO][CG];    // 18 KB: x halo, then packed bf16(k,v)
    __shared__ float qs[TILE * TILE][CG];  // 8 KB: q*log2e for interior pixels

    const int bid  = blockIdx.x;
    const int g    = bid & 7;
    const int tile = bid >> 3;
    const int tj   = tile % NT;
    const int ti   = (tile / NT) % NT;
    const int b    = tile / (NT * NT);

    const int t  = threadIdx.x;
    const int c  = t & 31;
    const int p0 = t >> 5;

    const int oc = g * CG + c;           // global out-channel
    const int h0 = ti * TILE - PAD, w0 = tj * TILE - PAD;

    // ---- Stage: x halo -> xs, coalesced float4 (1152 float4 over 256 thr).
#pragma unroll
    for (int r = 0; r < 5; ++r) {
        const int f = t + r * 256;
        if (f < NPIX_HALO * CG / 4) {
            const int hp = f >> 3, c4 = f & 7;        // 8 float4 per pixel
            const int hi = hp / HT, hj = hp % HT;
            const int gh = h0 + hi, gw = w0 + hj;
            float4 val = make_float4(0.f, 0.f, 0.f, 0.f);
            if (gh >= 0 && gh < TH && gw >= 0 && gw < TW)
                val = *(const float4*)(x + (((size_t)b * TH + gh) * TW + gw) * TC
                                         + g * CG + c4 * 4);
            *(float4*)&xs[hp][c4 * 4] = val;
        }
    }

    __syncthreads();   // stage -> merged pass

    // ---- Merged QKV pass over all 144 halo pixels (R12 shape).
    {
        float wqr[CG], wkr[CG], wvr[CG];
        const float4* wqp = (const float4*)(wq + (size_t)oc * CG);
        const float4* wkp = (const float4*)(wk + (size_t)oc * CG);
        const float4* wvp = (const float4*)(wv + (size_t)oc * CG);
#pragma unroll
        for (int i = 0; i < CG / 4; ++i) {
            float4 a = wqp[i], bb = wkp[i], cc = wvp[i];
            wqr[4*i+0]=a.x; wqr[4*i+1]=a.y; wqr[4*i+2]=a.z; wqr[4*i+3]=a.w;
            wkr[4*i+0]=bb.x; wkr[4*i+1]=bb.y; wkr[4*i+2]=bb.z; wkr[4*i+3]=bb.w;
            wvr[4*i+0]=cc.x; wvr[4*i+1]=cc.y; wvr[4*i+2]=cc.z; wvr[4*i+3]=cc.w;
        }
        const float qe = qemb[oc];

#pragma unroll 1   // rolled: keeps liveness flat
        for (int it = 0; it < NPIX_HALO / 8; ++it) {
            const int hp = it * 8 + p0;
            const int hi = hp / HT, hj = hp % HT;
            const float4* xp = (const float4*)&xs[hp][0];
            float aq = qe, ak = 0.f, av = 0.f;
#pragma unroll
            for (int i = 0; i < CG / 4; ++i) {
                const float4 xv = xp[i];   // LDS broadcast within half-wave
                aq = fmaf(wqr[4*i+0], xv.x, aq); ak = fmaf(wkr[4*i+0], xv.x, ak); av = fmaf(wvr[4*i+0], xv.x, av);
                aq = fmaf(wqr[4*i+1], xv.y, aq); ak = fmaf(wkr[4*i+1], xv.y, ak); av = fmaf(wvr[4*i+1], xv.y, av);
                aq = fmaf(wqr[4*i+2], xv.z, aq); ak = fmaf(wkr[4*i+2], xv.z, ak); av = fmaf(wvr[4*i+2], xv.z, av);
                aq = fmaf(wqr[4*i+3], xv.w, aq); ak = fmaf(wkr[4*i+3], xv.w, ak); av = fmaf(wvr[4*i+3], xv.w, av);
            }
            // pack k,v -> bf16 (round-half-up) in one u32; overwrite xs row
            // in place (all reads of this row happened above, same lanes).
            const unsigned kb = __float_as_uint(ak) + 0x8000u;
            const unsigned vb = __float_as_uint(av) + 0x8000u;
            ((unsigned*)&xs[hp][0])[c] = (kb >> 16) | (vb & 0xffff0000u);
            if (hi >= PAD && hi < PAD + TILE && hj >= PAD && hj < PAD + TILE)
                qs[(hi - PAD) * TILE + (hj - PAD)][c] = aq * LOG2E;
        }
    }

    // rel row -> 13 packed bf16 pairs (even idx = low half, odd = high half)
    unsigned relp[13];
    {
        const float* rp = rel + (size_t)oc * 25;
#pragma unroll
        for (int i = 0; i < 12; ++i) {
            const unsigned lo = __float_as_uint(rp[2 * i])     + 0x8000u;
            const unsigned hi = __float_as_uint(rp[2 * i + 1]) + 0x8000u;
            relp[i] = (lo >> 16) | (hi & 0xffff0000u);
        }
        relp[12] = (__float_as_uint(rp[24]) + 0x8000u) >> 16;
    }

    __syncthreads();   // merged pass -> C

    // q (already *log2e) for this thread's 8 column pixels
    float qreg[8];
#pragma unroll
    for (int ii = 0; ii < 8; ++ii) qreg[ii] = qs[ii * TILE + p0][c];

    // ---- Phase C: monolithic row-streaming attention (xs holds bf16 k,v).
    float s_[8], a_[8];
#pragma unroll
    for (int ii = 0; ii < 8; ++ii) { s_[ii] = 0.f; a_[ii] = 0.f; }

    const unsigned* kvp = (const unsigned*)&xs[0][0];
#pragma unroll
    for (int h = 0; h < HT; ++h) {
        float kr[5], vr[5];
#pragma unroll
        for (int j = 0; j < 5; ++j) {
            const unsigned u = kvp[(h * HT + p0 + j) * CG + c];
            kr[j] = __uint_as_float(u << 16);          // bf16 k -> f32
            vr[j] = __uint_as_float(u & 0xffff0000u);  // bf16 v -> f32
        }
#pragma unroll
        for (int ii = 0; ii < 8; ++ii) {
            const int di = h - ii;               // compile-time after unroll
            if (di >= 0 && di < 5) {
                const float qv = qreg[ii];
#pragma unroll
                for (int j = 0; j < 5; ++j) {
                    const int idx = di * 5 + j;  // compile-time
                    const unsigned ru = relp[idx >> 1];
                    const float rl = __uint_as_float((idx & 1) ? (ru & 0xffff0000u)
                                                               : (ru << 16));
                    const float e = __builtin_amdgcn_exp2f(qv * (kr[j] + rl));
                    s_[ii] += e;
                    a_[ii] = fmaf(e, vr[j], a_[ii]);
                }
            }
        }
    }

#pragma unroll
    for (int ii = 0; ii < 8; ++ii) {
        const int gh = ti * TILE + ii, gw = tj * TILE + p0;
        out[(((size_t)b * TH + gh) * TW + gw) * TC + g * CG + c] =
            a_[ii] * __builtin_amdgcn_rcpf(s_[ii]);
    }
}

extern "C" void kernel_launch(void* const* d_in, const int* in_sizes, int n_in,
                              void* d_out, int out_size, void* d_ws, size_t ws_size,
                              hipStream_t stream) {
    const float* x    = (const float*)d_in[0];
    const float* wq   = (const float*)d_in[1];
    const float* wk   = (const float*)d_in[2];
    const float* wv   = (const float*)d_in[3];
    const float* rel  = (const float*)d_in[4];
    const float* qemb = (const float*)d_in[5];
    float* out = (float*)d_out;

    const int nblocks = TB * NT * NT * G;   // 4*7*7*8 = 1568
    hipLaunchKernelGGL(fused_attn_conv_kernel, dim3(nblocks), dim3(256), 0, stream,
                       x, wq, wk, wv, rel, qemb, out);
}